// Round 2
// baseline (257.175 us; speedup 1.0000x reference)
//
#include <hip/hip_runtime.h>

#define DIM 4096
// SCALE = 1/sqrt(4096) = 1/64 exactly
#define FF_SCALE 0.015625f

// LDS float-index swizzle. XORs bits {5-7, 8-10, 11} down into bits 2-4
// (quad-granular). Effects:
//  - contiguous-per-thread b128 writes (lane stride 64 B): uniform 8 lanes
//    per bank-quad-slot -> structural-optimum b128 (~12 cyc)
//  - stride-64-float scalar reads/writes: exactly 2 lanes/bank = free (m136)
// Bijective (triangular XOR). Preserves i&3, so aligned 4-float groups stay
// contiguous and 16B-aligned -> float4 LDS ops remain legal.
__device__ __forceinline__ int phys(int i) {
    return i ^ ((((i >> 5) ^ (i >> 8) ^ (i >> 11)) & 7) << 2);
}

// 16-point unnormalized FWHT, natural stage order h=1,2,4,8 (matches ref).
__device__ __forceinline__ void fwht16(float v[16]) {
#pragma unroll
    for (int h = 1; h < 16; h <<= 1) {
#pragma unroll
        for (int i = 0; i < 16; ++i) {
            if ((i & h) == 0) {
                float a = v[i], b = v[i + h];
                v[i] = a + b;
                v[i + h] = a - b;
            }
        }
    }
}

// quad_perm DPP lane exchange (pure VALU; no LDS-pipe cost).
// CTRL 0xB1 = perm[1,0,3,2] (lane^1), 0x4E = perm[2,3,0,1] (lane^2).
template <int CTRL>
__device__ __forceinline__ float qperm(float x) {
    return __int_as_float(
        __builtin_amdgcn_mov_dpp(__float_as_int(x), CTRL, 0xF, 0xF, true));
}

// Butterfly over a quad lane-bit: even lane -> v+p, odd lane -> p-v.
// fmaf(v, +/-1, p) is exact, identical rounding to a+b / a-b.
template <int CTRL>
__device__ __forceinline__ void qbutterfly(float v[16], float s) {
#pragma unroll
    for (int e = 0; e < 16; ++e) {
        float p = qperm<CTRL>(v[e]);
        v[e] = fmaf(v[e], s, p);
    }
}

// One block per row. FWHT(4096) = radix-64 (bits 0-5) o radix-64 (bits 6-11).
// Round A: thread t owns contiguous i = t*16+c  -> reg stages 1..8, DPP 16,32.
// Round B: thread t owns strided  i = B + 64*c  -> reg stages 64..512,
//          DPP 1024,2048, where B = (t>>2) + (t&3)*1024.
// Global stage order is the natural ascending order -> bitwise identical to
// the reference butterfly tree.
__global__ __launch_bounds__(256) void fastfood_kernel(
    const float* __restrict__ x,
    const float* __restrict__ d1,
    const float* __restrict__ d2,
    const float* __restrict__ gauss_d,
    const int* __restrict__ perm,
    float* __restrict__ out)
{
    __shared__ float lds[DIM];
    const int t = threadIdx.x;
    const float s1 = (t & 1) ? -1.f : 1.f;   // sign for lane^1 stages
    const float s2 = (t & 2) ? -1.f : 1.f;   // sign for lane^2 stages
    const int B = (t >> 2) + ((t & 3) << 10);
    const size_t rowoff = (size_t)blockIdx.x * DIM;

    float v[16];

    // ---- load x*d1 (contiguous b128) ----
    {
        const float4* xv = (const float4*)(x + rowoff + t * 16);
        const float4* dv = (const float4*)(d1 + t * 16);
#pragma unroll
        for (int q = 0; q < 4; ++q) {
            float4 a = xv[q], d = dv[q];
            v[4 * q + 0] = a.x * d.x;
            v[4 * q + 1] = a.y * d.y;
            v[4 * q + 2] = a.z * d.z;
            v[4 * q + 3] = a.w * d.w;
        }
    }

    // ---- FWHT1 round A: strides 1..8 (reg) + 16,32 (DPP) ----
    fwht16(v);
    qbutterfly<0xB1>(v, s1);
    qbutterfly<0x4E>(v, s2);

    // transpose boundary: contiguous b128 writes (swizzled)
#pragma unroll
    for (int q = 0; q < 4; ++q)
        *(float4*)(lds + phys(t * 16 + 4 * q)) =
            make_float4(v[4 * q], v[4 * q + 1], v[4 * q + 2], v[4 * q + 3]);
    __syncthreads();  // B1

    // ---- FWHT1 round B: strides 64..512 (reg) + 1024,2048 (DPP) ----
    float w[16];
#pragma unroll
    for (int c = 0; c < 16; ++c) w[c] = lds[phys(B + (c << 6))];
    fwht16(w);
    qbutterfly<0xB1>(w, s1);
    qbutterfly<0x4E>(w, s2);
    // write back in place (same addresses this thread read)
#pragma unroll
    for (int c = 0; c < 16; ++c) lds[phys(B + (c << 6))] = w[c];
    __syncthreads();  // B2: FWHT1 result fully in LDS

    // ---- permutation gather + gauss_d * SCALE (FWHT2 input, contiguous) ----
    {
        const int4* pv = (const int4*)(perm + t * 16);
        const float4* gv = (const float4*)(gauss_d + t * 16);
#pragma unroll
        for (int q = 0; q < 4; ++q) {
            int4 p4 = pv[q];
            float4 g4 = gv[q];
            v[4 * q + 0] = lds[phys(p4.x)] * (g4.x * FF_SCALE);
            v[4 * q + 1] = lds[phys(p4.y)] * (g4.y * FF_SCALE);
            v[4 * q + 2] = lds[phys(p4.z)] * (g4.z * FF_SCALE);
            v[4 * q + 3] = lds[phys(p4.w)] * (g4.w * FF_SCALE);
        }
    }

    // ---- FWHT2 round A ----
    fwht16(v);
    qbutterfly<0xB1>(v, s1);
    qbutterfly<0x4E>(v, s2);
    __syncthreads();  // B3: all gather reads done before overwrite
#pragma unroll
    for (int q = 0; q < 4; ++q)
        *(float4*)(lds + phys(t * 16 + 4 * q)) =
            make_float4(v[4 * q], v[4 * q + 1], v[4 * q + 2], v[4 * q + 3]);
    __syncthreads();  // B4

    // ---- FWHT2 round B + fused d2 epilogue ----
#pragma unroll
    for (int c = 0; c < 16; ++c) w[c] = lds[phys(B + (c << 6))];
    fwht16(w);
    qbutterfly<0xB1>(w, s1);
    qbutterfly<0x4E>(w, s2);
    // stores: per instruction each 16-lane group writes a full 64 B segment
#pragma unroll
    for (int c = 0; c < 16; ++c) {
        int i = B + (c << 6);
        out[rowoff + i] = w[c] * d2[i];  // SCALE already folded at gather
    }
}

extern "C" void kernel_launch(void* const* d_in, const int* in_sizes, int n_in,
                              void* d_out, int out_size, void* d_ws, size_t ws_size,
                              hipStream_t stream) {
    const float* x       = (const float*)d_in[0];
    const float* d1      = (const float*)d_in[1];
    const float* d2      = (const float*)d_in[2];
    const float* gauss_d = (const float*)d_in[3];
    const int*   perm    = (const int*)d_in[4];
    float* out = (float*)d_out;

    const int batch = in_sizes[0] / DIM;  // 8192
    fastfood_kernel<<<batch, 256, 0, stream>>>(x, d1, d2, gauss_d, perm, out);
}

// Round 4
// 256.744 us; speedup vs baseline: 1.0017x; 1.0017x over previous
//
#include <hip/hip_runtime.h>

#define DIM 4096
// SCALE = 1/sqrt(4096) = 1/64 exactly
#define FF_SCALE 0.015625f

// Padded LDS layout: logical float index i lives at dword addr i + 4*(i>>6)
// (i.e. 64x64 matrix with leading-dim 68). Effects:
//  - A-round (contiguous 16/thread) float4 writes: 16B-aligned, uniform 8
//    lanes per bank-quad slot -> optimal b128.
//  - B-round (stride-64) addrs = base + 68*c with c static -> compiler merges
//    into ds_read2_b32 / ds_write2_b32 (2 elems per LDS op). 4-way bank
//    conflict accepted (1.58x, cheap; conflicts proved non-binding in r2).
//  - addressing is 2 VALU ops (vs ~6 for the r2 XOR swizzle), computed once.
__device__ __forceinline__ int pad(int i) { return i + ((i >> 6) << 2); }

// 16-point unnormalized FWHT, natural stage order h=1,2,4,8 (matches ref).
__device__ __forceinline__ void fwht16(float v[16]) {
#pragma unroll
    for (int h = 1; h < 16; h <<= 1) {
#pragma unroll
        for (int i = 0; i < 16; ++i) {
            if ((i & h) == 0) {
                float a = v[i], b = v[i + h];
                v[i] = a + b;
                v[i + h] = a - b;
            }
        }
    }
}

// quad_perm DPP lane exchange (pure VALU; no LDS-pipe cost).
// CTRL 0xB1 = perm[1,0,3,2] (lane^1), 0x4E = perm[2,3,0,1] (lane^2).
template <int CTRL>
__device__ __forceinline__ float qperm(float x) {
    return __int_as_float(
        __builtin_amdgcn_mov_dpp(__float_as_int(x), CTRL, 0xF, 0xF, true));
}

// Butterfly over a quad lane-bit: low lane -> v+p, high lane -> p-v.
// fmaf(v, +/-1, p) is exact, identical rounding to a+b / a-b.
template <int CTRL>
__device__ __forceinline__ void qbutterfly(float v[16], float s) {
#pragma unroll
    for (int e = 0; e < 16; ++e) {
        float p = qperm<CTRL>(v[e]);
        v[e] = fmaf(v[e], s, p);
    }
}

// One block per row. FWHT(4096) = radix-64 (bits 0-5) o radix-64 (bits 6-11).
// A-round: thread t owns i = 16t+j  -> reg stages 1..8, DPP stages 16,32.
// B-round: thread t owns i = B+64c  -> reg stages 64..512, DPP 1024,2048,
//          with B = (t>>2) + 1024*(t&3)  (bits 10-11 of i <-> lane bits 0-1).
// Natural ascending stage order -> identical butterfly tree to reference.
__global__ __launch_bounds__(256, 8) void fastfood_kernel(
    const float* __restrict__ x,
    const float* __restrict__ d1,
    const float* __restrict__ d2,
    const float* __restrict__ gauss_d,
    const int* __restrict__ perm,
    float* __restrict__ out)
{
    __shared__ float lds[64 * 68];  // 17408 B -> 8 blocks/CU (wave-limited)
    const int t = threadIdx.x;
    const float s1 = (t & 1) ? -1.f : 1.f;   // sign for lane^1 stages
    const float s2 = (t & 2) ? -1.f : 1.f;   // sign for lane^2 stages
    const size_t rowoff = (size_t)blockIdx.x * DIM;

    // A-round base dword addr: pad(16t) = 16t + 4*(t>>2); contiguous in j.
    const int aBase = 16 * t + ((t >> 2) << 2);
    // B-round: pad(B + 64c) = bBase + 68c (bit-fields disjoint, no carries).
    const int bBase = (t >> 2) + 1088 * (t & 3);

    float v[16];

    // ---- load x*d1 (contiguous float4, coalesced) ----
    {
        const float4* xv = (const float4*)(x + rowoff + t * 16);
        const float4* dv = (const float4*)(d1 + t * 16);
#pragma unroll
        for (int q = 0; q < 4; ++q) {
            float4 a = xv[q], d = dv[q];
            v[4 * q + 0] = a.x * d.x;
            v[4 * q + 1] = a.y * d.y;
            v[4 * q + 2] = a.z * d.z;
            v[4 * q + 3] = a.w * d.w;
        }
    }

    // ---- FWHT1 A-round: h=1..8 (regs) + 16,32 (DPP) ----
    fwht16(v);
    qbutterfly<0xB1>(v, s1);
    qbutterfly<0x4E>(v, s2);
#pragma unroll
    for (int q = 0; q < 4; ++q)
        *(float4*)(lds + aBase + 4 * q) =
            make_float4(v[4 * q], v[4 * q + 1], v[4 * q + 2], v[4 * q + 3]);
    __syncthreads();  // B1

    // ---- FWHT1 B-round: h=64..512 (regs) + 1024,2048 (DPP) ----
#pragma unroll
    for (int g = 0; g < 4; ++g) {
        const int bg = bBase + 272 * g;
#pragma unroll
        for (int m = 0; m < 4; ++m) v[4 * g + m] = lds[bg + 68 * m];
    }
    fwht16(v);
    qbutterfly<0xB1>(v, s1);
    qbutterfly<0x4E>(v, s2);
#pragma unroll
    for (int g = 0; g < 4; ++g) {
        const int bg = bBase + 272 * g;
#pragma unroll
        for (int m = 0; m < 4; ++m) lds[bg + 68 * m] = v[4 * g + m];
    }
    __syncthreads();  // B2: FWHT1 result fully in LDS

    // ---- permutation gather + gauss (FWHT2 input, contiguous j = 16t+k) ----
    {
        const int4* pv = (const int4*)(perm + t * 16);
        const float4* gv = (const float4*)(gauss_d + t * 16);
#pragma unroll
        for (int q = 0; q < 4; ++q) {
            int4 p4 = pv[q];
            float4 g4 = gv[q];
            v[4 * q + 0] = lds[pad(p4.x)] * g4.x;
            v[4 * q + 1] = lds[pad(p4.y)] * g4.y;
            v[4 * q + 2] = lds[pad(p4.z)] * g4.z;
            v[4 * q + 3] = lds[pad(p4.w)] * g4.w;
        }
    }

    // ---- FWHT2 A-round (register-only; overlaps barrier wait) ----
    fwht16(v);
    qbutterfly<0xB1>(v, s1);
    qbutterfly<0x4E>(v, s2);
    __syncthreads();  // B3: all gather reads done before overwrite
#pragma unroll
    for (int q = 0; q < 4; ++q)
        *(float4*)(lds + aBase + 4 * q) =
            make_float4(v[4 * q], v[4 * q + 1], v[4 * q + 2], v[4 * q + 3]);
    __syncthreads();  // B4

    // ---- FWHT2 B-round + fused d2*SCALE epilogue ----
#pragma unroll
    for (int g = 0; g < 4; ++g) {
        const int bg = bBase + 272 * g;
#pragma unroll
        for (int m = 0; m < 4; ++m) v[4 * g + m] = lds[bg + 68 * m];
    }
    fwht16(v);
    qbutterfly<0xB1>(v, s1);
    qbutterfly<0x4E>(v, s2);
    {
        const int B = (t >> 2) + ((t & 3) << 10);
        const float* d2p = d2 + B;
        float* op = out + rowoff + B;
        // per instr: 4 segments of 64 contiguous bytes (one per lane quad)
#pragma unroll
        for (int c = 0; c < 16; ++c)
            op[64 * c] = (v[c] * d2p[64 * c]) * FF_SCALE;
    }
}

extern "C" void kernel_launch(void* const* d_in, const int* in_sizes, int n_in,
                              void* d_out, int out_size, void* d_ws, size_t ws_size,
                              hipStream_t stream) {
    const float* x       = (const float*)d_in[0];
    const float* d1      = (const float*)d_in[1];
    const float* d2      = (const float*)d_in[2];
    const float* gauss_d = (const float*)d_in[3];
    const int*   perm    = (const int*)d_in[4];
    float* out = (float*)d_out;

    const int batch = in_sizes[0] / DIM;  // 8192
    fastfood_kernel<<<batch, 256, 0, stream>>>(x, d1, d2, gauss_d, perm, out);
}